// Round 1
// baseline (1595.495 us; speedup 1.0000x reference)
//
#include <hip/hip_runtime.h>

typedef __bf16 bf16;
typedef __bf16 bf16x4 __attribute__((ext_vector_type(4)));
typedef __bf16 bf16x8 __attribute__((ext_vector_type(8)));
typedef float f32x4 __attribute__((ext_vector_type(4)));

#define LOG2E 1.44269504088896340736f

// ---------------- async global->LDS (width 16) ----------------
__device__ __forceinline__ void gload_lds16(const void* gp, void* lp) {
    __builtin_amdgcn_global_load_lds(
        (__attribute__((address_space(1))) void*)gp,
        (__attribute__((address_space(3))) void*)lp,
        16, 0, 0);
}

// ---------------- fp32 -> bf16 convert ----------------
__global__ void conv_bf16(const float* __restrict__ in, bf16* __restrict__ out, int n4) {
    int i = blockIdx.x * 256 + threadIdx.x;
    if (i < n4) {
        float4 f = ((const float4*)in)[i];
        bf16x4 v;
        v[0] = (bf16)f.x; v[1] = (bf16)f.y; v[2] = (bf16)f.z; v[3] = (bf16)f.w;
        *(bf16x4*)(out + (size_t)i * 4) = v;
    }
}

// ---------------- cached_k -> d_out(k, t<2048) fp32 + kb bf16 ----------------
// cached_k layout (B,H,2048,128) -> dest layout (B,H,4096,128) at t<2048
__global__ void copy_cache_k(const float* __restrict__ ck, float* __restrict__ kout,
                             bf16* __restrict__ kb) {
    size_t i = ((size_t)blockIdx.x * 256 + threadIdx.x) * 4;  // over 8,388,608 elts
    size_t bh  = i >> 18;          // / (2048*128)
    size_t rem = i & 262143;
    size_t o   = (bh << 19) + rem; // bh * 4096*128 + rem
    float4 f = *(const float4*)(ck + i);
    *(float4*)(kout + o) = f;
    bf16x4 v;
    v[0] = (bf16)f.x; v[1] = (bf16)f.y; v[2] = (bf16)f.z; v[3] = (bf16)f.w;
    *(bf16x4*)(kb + o) = v;
}

// ---------------- cached_v -> d_out(v, t<2048) fp32 + vtb bf16 transposed ----------------
// cached_v (B,H,2048,128); vtb layout (B,H,128,4096), cols t<2048
__global__ void copy_cache_v(const float* __restrict__ cv, float* __restrict__ vout,
                             bf16* __restrict__ vtb) {
    __shared__ float tile[32][33];
    int bh = blockIdx.z;
    int t0 = blockIdx.x * 32;
    int dh0 = blockIdx.y * 32;
    int tx = threadIdx.x, ty = threadIdx.y;
    const float* src = cv + (size_t)bh * 2048 * 128;
    float* dstf = vout + (size_t)bh * 4096 * 128;
    #pragma unroll
    for (int i = 0; i < 4; ++i) {
        int t = t0 + ty * 4 + i;
        float val = src[(size_t)t * 128 + dh0 + tx];
        dstf[(size_t)t * 128 + dh0 + tx] = val;
        tile[ty * 4 + i][tx] = val;  // [t_local][dh_local]
    }
    __syncthreads();
    bf16* dstb = vtb + (size_t)bh * 128 * 4096;
    #pragma unroll
    for (int i = 0; i < 4; ++i) {
        int dh = dh0 + ty * 4 + i;
        dstb[(size_t)dh * 4096 + t0 + tx] = (bf16)tile[tx][ty * 4 + i];
    }
}

// ---------------- NT GEMM: C[M,N] = A[M,K] * B[N,K]^T, bf16 in, fp32 acc ----------------
// M=4096, N=2048, K=2048. 128x128 block tile, BK=32, 256 thr (4 waves, 64x64 each).
// MODE 0: fp32 row-major -> out_f32
// MODE 1: bf16 -> out_bf16 at [b][h][s][dh] (q layout)
// MODE 2: fp32 -> out_f32 at [b][h][2048+s][dh] AND bf16 -> out_bf16 same index (k)
// MODE 3: fp32 -> out_f32 at [b][h][2048+s][dh] AND bf16 -> out_bf16 at [b][h][dh][2048+s] (v)
template <int MODE>
__global__ __launch_bounds__(256)
void gemm_nt(const bf16* __restrict__ A, const bf16* __restrict__ Bm,
             float* __restrict__ out_f32, bf16* __restrict__ out_bf16) {
    const int K = 2048, N = 2048;
    __shared__ __align__(16) char smem[16384];  // A tile 8KB @0, B tile 8KB @8192
    const int tid = threadIdx.x;
    const int wid = tid >> 6;
    const int lane = tid & 63;
    const int quad = lane >> 4;
    const int l16 = lane & 15;
    const int m0 = blockIdx.y * 128;
    const int n0 = blockIdx.x * 128;
    const int wm = (wid & 1) * 64;
    const int wn = (wid >> 1) * 64;

    f32x4 zero = {0.f, 0.f, 0.f, 0.f};
    f32x4 acc[4][4];
    #pragma unroll
    for (int i = 0; i < 4; ++i)
        #pragma unroll
        for (int j = 0; j < 4; ++j) acc[i][j] = zero;

    for (int k0 = 0; k0 < K; k0 += 32) {
        #pragma unroll
        for (int t = 0; t < 2; ++t) {
            int c = t * 256 + tid;
            int row = c >> 2, kc = c & 3;
            const char* gA = (const char*)(A + (size_t)(m0 + row) * K + k0 + kc * 8);
            const char* gB = (const char*)(Bm + (size_t)(n0 + row) * K + k0 + kc * 8);
            char* lA = smem + (size_t)(t * 256 + (tid & ~63)) * 16;
            char* lB = smem + 8192 + (size_t)(t * 256 + (tid & ~63)) * 16;
            gload_lds16(gA, lA);
            gload_lds16(gB, lB);
        }
        __syncthreads();
        bf16x8 af[4], bfv[4];
        #pragma unroll
        for (int i = 0; i < 4; ++i) {
            af[i]  = *(const bf16x8*)(smem + ((wm + i * 16 + l16) * 32 + quad * 8) * 2);
            bfv[i] = *(const bf16x8*)(smem + 8192 + ((wn + i * 16 + l16) * 32 + quad * 8) * 2);
        }
        #pragma unroll
        for (int i = 0; i < 4; ++i)
            #pragma unroll
            for (int j = 0; j < 4; ++j)
                acc[i][j] = __builtin_amdgcn_mfma_f32_16x16x32_bf16(af[i], bfv[j], acc[i][j], 0, 0, 0);
        __syncthreads();
    }

    #pragma unroll
    for (int i = 0; i < 4; ++i)
        #pragma unroll
        for (int j = 0; j < 4; ++j)
            #pragma unroll
            for (int r = 0; r < 4; ++r) {
                int grow = m0 + wm + i * 16 + quad * 4 + r;  // 0..4095 = b*2048+s
                int gcol = n0 + wn + j * 16 + l16;           // 0..2047 = h*128+dh
                float v = acc[i][j][r];
                if (MODE == 0) {
                    out_f32[(size_t)grow * N + gcol] = v;
                } else {
                    int b = grow >> 11, s = grow & 2047;
                    int h = gcol >> 7, dh = gcol & 127;
                    if (MODE == 1) {
                        out_bf16[(((size_t)(b * 16 + h) * 2048) + s) * 128 + dh] = (bf16)v;
                    } else if (MODE == 2) {
                        size_t idx = (((size_t)(b * 16 + h) * 4096) + 2048 + s) * 128 + dh;
                        out_f32[idx] = v;
                        out_bf16[idx] = (bf16)v;
                    } else {
                        size_t idx = (((size_t)(b * 16 + h) * 4096) + 2048 + s) * 128 + dh;
                        out_f32[idx] = v;
                        out_bf16[(((size_t)(b * 16 + h) * 128) + dh) * 4096 + 2048 + s] = (bf16)v;
                    }
                }
            }
}

// ---------------- flash attention ----------------
// qb (B,H,2048,128) bf16; kb (B,H,4096,128) bf16; vtb (B,H,128,4096) bf16
// -> ab (B,S,2048) bf16 at [b][s][h*128+dh]
__global__ __launch_bounds__(256)
void flash_attn(const bf16* __restrict__ qb, const bf16* __restrict__ kb,
                const bf16* __restrict__ vtb, bf16* __restrict__ ab) {
    __shared__ __align__(16) bf16 pbuf[4][16 * 64];
    const int tid = threadIdx.x;
    const int wid = tid >> 6;
    const int lane = tid & 63;
    const int quad = lane >> 4;
    const int l16 = lane & 15;
    const int bh = blockIdx.y;
    const int b = bh >> 4, h = bh & 15;
    const int s0 = blockIdx.x * 64 + wid * 16;

    const bf16* Q  = qb  + (size_t)bh * 2048 * 128;
    const bf16* Kp = kb  + (size_t)bh * 4096 * 128;
    const bf16* Vt = vtb + (size_t)bh * 128 * 4096;

    bf16x8 qf[4];
    #pragma unroll
    for (int ks = 0; ks < 4; ++ks)
        qf[ks] = *(const bf16x8*)(Q + (size_t)(s0 + l16) * 128 + ks * 32 + quad * 8);

    f32x4 zero = {0.f, 0.f, 0.f, 0.f};
    f32x4 oacc[8];
    #pragma unroll
    for (int i = 0; i < 8; ++i) oacc[i] = zero;
    float mrun[4], lrun[4];
    #pragma unroll
    for (int r = 0; r < 4; ++r) { mrun[r] = -1e30f; lrun[r] = 0.f; }

    const float scale = 0.08838834764831845f;  // 1/sqrt(128)

    for (int t0 = 0; t0 < 4096; t0 += 64) {
        f32x4 sacc[4];
        #pragma unroll
        for (int nt = 0; nt < 4; ++nt) sacc[nt] = zero;
        #pragma unroll
        for (int nt = 0; nt < 4; ++nt) {
            #pragma unroll
            for (int ks = 0; ks < 4; ++ks) {
                bf16x8 kf = *(const bf16x8*)(Kp + (size_t)(t0 + nt * 16 + l16) * 128 + ks * 32 + quad * 8);
                sacc[nt] = __builtin_amdgcn_mfma_f32_16x16x32_bf16(qf[ks], kf, sacc[nt], 0, 0, 0);
            }
        }
        // online softmax over the 64 cols of this tile (rows = quad*4+r)
        float mx[4];
        #pragma unroll
        for (int r = 0; r < 4; ++r) {
            float v0 = fmaxf(fmaxf(sacc[0][r], sacc[1][r]), fmaxf(sacc[2][r], sacc[3][r])) * scale;
            #pragma unroll
            for (int d = 1; d < 16; d <<= 1) v0 = fmaxf(v0, __shfl_xor(v0, d));
            mx[r] = v0;
        }
        float alpha[4], mnew[4], rsum[4];
        #pragma unroll
        for (int r = 0; r < 4; ++r) {
            mnew[r] = fmaxf(mrun[r], mx[r]);
            alpha[r] = exp2f((mrun[r] - mnew[r]) * LOG2E);
            rsum[r] = 0.f;
        }
        #pragma unroll
        for (int nt = 0; nt < 4; ++nt)
            #pragma unroll
            for (int r = 0; r < 4; ++r) {
                float p = exp2f((sacc[nt][r] * scale - mnew[r]) * LOG2E);
                sacc[nt][r] = p;
                rsum[r] += p;
            }
        #pragma unroll
        for (int r = 0; r < 4; ++r) {
            float v0 = rsum[r];
            #pragma unroll
            for (int d = 1; d < 16; d <<= 1) v0 += __shfl_xor(v0, d);
            lrun[r] = lrun[r] * alpha[r] + v0;
            mrun[r] = mnew[r];
        }
        #pragma unroll
        for (int i = 0; i < 8; ++i)
            #pragma unroll
            for (int r = 0; r < 4; ++r) oacc[i][r] *= alpha[r];

        // P: C-layout regs -> LDS -> A-layout frags
        __syncthreads();  // WAR vs previous iteration's reads
        #pragma unroll
        for (int nt = 0; nt < 4; ++nt)
            #pragma unroll
            for (int r = 0; r < 4; ++r)
                pbuf[wid][(quad * 4 + r) * 64 + nt * 16 + l16] = (bf16)sacc[nt][r];
        __syncthreads();
        bf16x8 pf[2];
        #pragma unroll
        for (int ks = 0; ks < 2; ++ks)
            pf[ks] = *(const bf16x8*)(&pbuf[wid][l16 * 64 + ks * 32 + quad * 8]);
        #pragma unroll
        for (int dht = 0; dht < 8; ++dht) {
            #pragma unroll
            for (int ks = 0; ks < 2; ++ks) {
                bf16x8 vf = *(const bf16x8*)(Vt + (size_t)(dht * 16 + l16) * 4096 + t0 + ks * 32 + quad * 8);
                oacc[dht] = __builtin_amdgcn_mfma_f32_16x16x32_bf16(pf[ks], vf, oacc[dht], 0, 0, 0);
            }
        }
    }

    #pragma unroll
    for (int dht = 0; dht < 8; ++dht)
        #pragma unroll
        for (int r = 0; r < 4; ++r) {
            int s = s0 + quad * 4 + r;
            float v = oacc[dht][r] / lrun[r];
            ab[((size_t)(b * 2048 + s)) * 2048 + h * 128 + dht * 16 + l16] = (bf16)v;
        }
}

// ---------------- launch ----------------
extern "C" void kernel_launch(void* const* d_in, const int* in_sizes, int n_in,
                              void* d_out, int out_size, void* d_ws, size_t ws_size,
                              hipStream_t stream) {
    const float* x        = (const float*)d_in[0];
    const float* cached_k = (const float*)d_in[1];
    const float* cached_v = (const float*)d_in[2];
    const float* W_q      = (const float*)d_in[3];
    const float* W_k      = (const float*)d_in[4];
    const float* W_v      = (const float*)d_in[5];
    const float* W_o      = (const float*)d_in[6];

    float* out  = (float*)d_out;              // (2,2048,2048)
    float* kout = out + 8388608;              // (2,16,4096,128)
    float* vout = out + 25165824;             // (2,16,4096,128)

    char* ws = (char*)d_ws;
    size_t off = 0;
    auto alloc = [&](size_t elts) { bf16* p = (bf16*)(ws + off); off += elts * 2; return p; };
    bf16* xb  = alloc(8388608);   // x bf16 (4096,2048)
    bf16* wqb = alloc(4194304);
    bf16* wkb = alloc(4194304);
    bf16* wvb = alloc(4194304);
    bf16* wob = alloc(4194304);
    bf16* qb  = alloc(8388608);   // (B,H,2048,128)
    bf16* kb  = alloc(16777216);  // (B,H,4096,128)
    bf16* vtb = alloc(16777216);  // (B,H,128,4096)
    bf16* ab  = alloc(8388608);   // (B,S,2048)

    conv_bf16<<<8192, 256, 0, stream>>>(x, xb, 2097152);
    conv_bf16<<<4096, 256, 0, stream>>>(W_q, wqb, 1048576);
    conv_bf16<<<4096, 256, 0, stream>>>(W_k, wkb, 1048576);
    conv_bf16<<<4096, 256, 0, stream>>>(W_v, wvb, 1048576);
    conv_bf16<<<4096, 256, 0, stream>>>(W_o, wob, 1048576);
    copy_cache_k<<<8192, 256, 0, stream>>>(cached_k, kout, kb);
    copy_cache_v<<<dim3(64, 4, 32), dim3(32, 8), 0, stream>>>(cached_v, vout, vtb);

    gemm_nt<1><<<dim3(16, 32), 256, 0, stream>>>(xb, wqb, nullptr, qb);
    gemm_nt<2><<<dim3(16, 32), 256, 0, stream>>>(xb, wkb, kout, kb);
    gemm_nt<3><<<dim3(16, 32), 256, 0, stream>>>(xb, wvb, vout, vtb);

    flash_attn<<<dim3(32, 32), 256, 0, stream>>>(qb, kb, vtb, ab);

    gemm_nt<0><<<dim3(16, 32), 256, 0, stream>>>(ab, wob, out, nullptr);
}

// Round 2
// 1051.900 us; speedup vs baseline: 1.5168x; 1.5168x over previous
//
#include <hip/hip_runtime.h>

typedef __bf16 bf16;
typedef __bf16 bf16x4 __attribute__((ext_vector_type(4)));
typedef __bf16 bf16x8 __attribute__((ext_vector_type(8)));
typedef float f32x4 __attribute__((ext_vector_type(4)));

#define LOG2E 1.44269504088896340736f
// 1/sqrt(128) * log2(e), folded into Q at projection time -> softmax runs in log2 domain
#define QSCALE 0.12751884935f

// ---------------- async global->LDS (width 16) ----------------
__device__ __forceinline__ void gload_lds16(const void* gp, void* lp) {
    __builtin_amdgcn_global_load_lds(
        (__attribute__((address_space(1))) void*)gp,
        (__attribute__((address_space(3))) void*)lp,
        16, 0, 0);
}

// XOR swizzle of 16B-chunk index within a row (low 3 bits), self-inverse.
__device__ __forceinline__ int swz(int j, int row) {
    return (j & 8) | ((j ^ row) & 7);
}

// ---------------- fp32 -> bf16 convert ----------------
__global__ void conv_bf16(const float* __restrict__ in, bf16* __restrict__ out, int n4) {
    int i = blockIdx.x * 256 + threadIdx.x;
    if (i < n4) {
        float4 f = ((const float4*)in)[i];
        bf16x4 v;
        v[0] = (bf16)f.x; v[1] = (bf16)f.y; v[2] = (bf16)f.z; v[3] = (bf16)f.w;
        *(bf16x4*)(out + (size_t)i * 4) = v;
    }
}

// ---------------- cached_k -> d_out(k, t<2048) fp32 + kb bf16 ----------------
__global__ void copy_cache_k(const float* __restrict__ ck, float* __restrict__ kout,
                             bf16* __restrict__ kb) {
    size_t i = ((size_t)blockIdx.x * 256 + threadIdx.x) * 4;
    size_t bh  = i >> 18;
    size_t rem = i & 262143;
    size_t o   = (bh << 19) + rem;
    float4 f = *(const float4*)(ck + i);
    *(float4*)(kout + o) = f;
    bf16x4 v;
    v[0] = (bf16)f.x; v[1] = (bf16)f.y; v[2] = (bf16)f.z; v[3] = (bf16)f.w;
    *(bf16x4*)(kb + o) = v;
}

// ---------------- cached_v -> d_out(v, t<2048) fp32 + vtb bf16 transposed ----------------
__global__ void copy_cache_v(const float* __restrict__ cv, float* __restrict__ vout,
                             bf16* __restrict__ vtb) {
    __shared__ float tile[32][33];
    int bh = blockIdx.z;
    int t0 = blockIdx.x * 32;
    int dh0 = blockIdx.y * 32;
    int tx = threadIdx.x, ty = threadIdx.y;
    const float* src = cv + (size_t)bh * 2048 * 128;
    float* dstf = vout + (size_t)bh * 4096 * 128;
    #pragma unroll
    for (int i = 0; i < 4; ++i) {
        int t = t0 + ty * 4 + i;
        float val = src[(size_t)t * 128 + dh0 + tx];
        dstf[(size_t)t * 128 + dh0 + tx] = val;
        tile[ty * 4 + i][tx] = val;
    }
    __syncthreads();
    bf16* dstb = vtb + (size_t)bh * 128 * 4096;
    #pragma unroll
    for (int i = 0; i < 4; ++i) {
        int dh = dh0 + ty * 4 + i;
        dstb[(size_t)dh * 4096 + t0 + tx] = (bf16)tile[tx][ty * 4 + i];
    }
}

// ---------------- NT GEMM: C[M,N] = A[M,K] * B[N,K]^T, bf16 in, fp32 acc ----------------
// MODE 0: fp32 row-major; MODE 1: q layout bf16 (pre-scaled by QSCALE);
// MODE 2: k fp32+bf16; MODE 3: v fp32 + transposed bf16
template <int MODE>
__global__ __launch_bounds__(256)
void gemm_nt(const bf16* __restrict__ A, const bf16* __restrict__ Bm,
             float* __restrict__ out_f32, bf16* __restrict__ out_bf16) {
    const int K = 2048, N = 2048;
    __shared__ __align__(16) char smem[16384];
    const int tid = threadIdx.x;
    const int wid = tid >> 6;
    const int lane = tid & 63;
    const int quad = lane >> 4;
    const int l16 = lane & 15;
    const int m0 = blockIdx.y * 128;
    const int n0 = blockIdx.x * 128;
    const int wm = (wid & 1) * 64;
    const int wn = (wid >> 1) * 64;

    f32x4 zero = {0.f, 0.f, 0.f, 0.f};
    f32x4 acc[4][4];
    #pragma unroll
    for (int i = 0; i < 4; ++i)
        #pragma unroll
        for (int j = 0; j < 4; ++j) acc[i][j] = zero;

    for (int k0 = 0; k0 < K; k0 += 32) {
        #pragma unroll
        for (int t = 0; t < 2; ++t) {
            int c = t * 256 + tid;
            int row = c >> 2, kc = c & 3;
            const char* gA = (const char*)(A + (size_t)(m0 + row) * K + k0 + kc * 8);
            const char* gB = (const char*)(Bm + (size_t)(n0 + row) * K + k0 + kc * 8);
            char* lA = smem + (size_t)(t * 256 + (tid & ~63)) * 16;
            char* lB = smem + 8192 + (size_t)(t * 256 + (tid & ~63)) * 16;
            gload_lds16(gA, lA);
            gload_lds16(gB, lB);
        }
        __syncthreads();
        bf16x8 af[4], bfv[4];
        #pragma unroll
        for (int i = 0; i < 4; ++i) {
            af[i]  = *(const bf16x8*)(smem + ((wm + i * 16 + l16) * 32 + quad * 8) * 2);
            bfv[i] = *(const bf16x8*)(smem + 8192 + ((wn + i * 16 + l16) * 32 + quad * 8) * 2);
        }
        #pragma unroll
        for (int i = 0; i < 4; ++i)
            #pragma unroll
            for (int j = 0; j < 4; ++j)
                acc[i][j] = __builtin_amdgcn_mfma_f32_16x16x32_bf16(af[i], bfv[j], acc[i][j], 0, 0, 0);
        __syncthreads();
    }

    #pragma unroll
    for (int i = 0; i < 4; ++i)
        #pragma unroll
        for (int j = 0; j < 4; ++j)
            #pragma unroll
            for (int r = 0; r < 4; ++r) {
                int grow = m0 + wm + i * 16 + quad * 4 + r;
                int gcol = n0 + wn + j * 16 + l16;
                float v = acc[i][j][r];
                if (MODE == 0) {
                    out_f32[(size_t)grow * N + gcol] = v;
                } else {
                    int b = grow >> 11, s = grow & 2047;
                    int h = gcol >> 7, dh = gcol & 127;
                    if (MODE == 1) {
                        out_bf16[(((size_t)(b * 16 + h) * 2048) + s) * 128 + dh] = (bf16)(v * QSCALE);
                    } else if (MODE == 2) {
                        size_t idx = (((size_t)(b * 16 + h) * 4096) + 2048 + s) * 128 + dh;
                        out_f32[idx] = v;
                        out_bf16[idx] = (bf16)v;
                    } else {
                        size_t idx = (((size_t)(b * 16 + h) * 4096) + 2048 + s) * 128 + dh;
                        out_f32[idx] = v;
                        out_bf16[(((size_t)(b * 16 + h) * 128) + dh) * 4096 + 2048 + s] = (bf16)v;
                    }
                }
            }
}

// ---------------- flash attention v2 ----------------
// qb (B,H,2048,128) bf16 PRE-SCALED by QSCALE; kb (B,H,4096,128); vtb (B,H,128,4096)
// -> ab (B,S,2048) bf16.
// Block: 256 thr (4 waves); wave owns 32 Q rows (2 x 16-row tiles); block = 128 rows.
// Per T-tile (64): stage K(64x128)+Vt(128x64) to LDS (swizzled), m97 2-barrier loop.
// pbuf is per-wave (no barriers). Softmax in log2 domain (exp2 only).
__global__ __launch_bounds__(256, 3)
void flash_attn(const bf16* __restrict__ qb, const bf16* __restrict__ kb,
                const bf16* __restrict__ vtb, bf16* __restrict__ ab) {
    // LDS: K tile [0,16384), V tile [16384,32768), pbuf [32768, 49152)
    __shared__ __align__(16) char smem[49152];
    const int tid = threadIdx.x;
    const int wid = tid >> 6;
    const int lane = tid & 63;
    const int quad = lane >> 4;
    const int l16 = lane & 15;
    const int bh = blockIdx.y;
    const int b = bh >> 4, h = bh & 15;
    const int s0 = blockIdx.x * 128 + wid * 32;

    const bf16* Q  = qb  + (size_t)bh * 2048 * 128;
    const bf16* Kp = kb  + (size_t)bh * 4096 * 128;
    const bf16* Vt = vtb + (size_t)bh * 128 * 4096;

    // Q fragments for 2 row-tiles, kept in registers (32 VGPR)
    bf16x8 qf[2][4];
    #pragma unroll
    for (int qi = 0; qi < 2; ++qi)
        #pragma unroll
        for (int ks = 0; ks < 4; ++ks)
            qf[qi][ks] = *(const bf16x8*)(Q + (size_t)(s0 + qi * 16 + l16) * 128 + ks * 32 + quad * 8);

    f32x4 zero = {0.f, 0.f, 0.f, 0.f};
    f32x4 oacc[2][8];
    float mrun[2][4], lrun[2][4];
    #pragma unroll
    for (int qi = 0; qi < 2; ++qi) {
        #pragma unroll
        for (int i = 0; i < 8; ++i) oacc[qi][i] = zero;
        #pragma unroll
        for (int r = 0; r < 4; ++r) { mrun[qi][r] = -1e30f; lrun[qi][r] = 0.f; }
    }

    char* const Ksh = smem;
    char* const Vsh = smem + 16384;

    for (int t0 = 0; t0 < 4096; t0 += 64) {
        __syncthreads();  // previous iteration's LDS reads done
        // ---- stage K tile: 64 rows x 256B = 1024 chunks of 16B ----
        #pragma unroll
        for (int r = 0; r < 4; ++r) {
            int kc = r * 256 + tid;
            int row = kc >> 4, p = kc & 15;
            int j = swz(p, row);
            gload_lds16(Kp + (size_t)(t0 + row) * 128 + j * 8, Ksh + kc * 16);
        }
        // ---- stage V tile: 128 rows x 128B = 1024 chunks ----
        #pragma unroll
        for (int r = 0; r < 4; ++r) {
            int vc = r * 256 + tid;
            int row = vc >> 3, p = vc & 7;
            int j = (p ^ row) & 7;
            gload_lds16(Vt + (size_t)row * 4096 + t0 + j * 8, Vsh + vc * 16);
        }
        __syncthreads();  // tiles ready (barrier drains vmcnt)

        // ---- QK^T: 16 kf reads, 32 MFMA ----
        f32x4 sacc[2][4];
        #pragma unroll
        for (int qi = 0; qi < 2; ++qi)
            #pragma unroll
            for (int nt = 0; nt < 4; ++nt) sacc[qi][nt] = zero;
        #pragma unroll
        for (int nt = 0; nt < 4; ++nt) {
            #pragma unroll
            for (int ks = 0; ks < 4; ++ks) {
                bf16x8 kf = *(const bf16x8*)(Ksh + (nt * 16 + l16) * 256 + swz(ks * 4 + quad, l16) * 16);
                sacc[0][nt] = __builtin_amdgcn_mfma_f32_16x16x32_bf16(qf[0][ks], kf, sacc[0][nt], 0, 0, 0);
                sacc[1][nt] = __builtin_amdgcn_mfma_f32_16x16x32_bf16(qf[1][ks], kf, sacc[1][nt], 0, 0, 0);
            }
        }

        // ---- online softmax (log2 domain; scores already scaled) ----
        #pragma unroll
        for (int qi = 0; qi < 2; ++qi) {
            float mx[4];
            #pragma unroll
            for (int r = 0; r < 4; ++r) {
                float v0 = fmaxf(fmaxf(sacc[qi][0][r], sacc[qi][1][r]),
                                 fmaxf(sacc[qi][2][r], sacc[qi][3][r]));
                #pragma unroll
                for (int d = 1; d < 16; d <<= 1) v0 = fmaxf(v0, __shfl_xor(v0, d));
                mx[r] = v0;
            }
            float alpha[4], mnew[4], rsum[4];
            #pragma unroll
            for (int r = 0; r < 4; ++r) {
                mnew[r] = fmaxf(mrun[qi][r], mx[r]);
                alpha[r] = exp2f(mrun[qi][r] - mnew[r]);
                rsum[r] = 0.f;
            }
            #pragma unroll
            for (int nt = 0; nt < 4; ++nt)
                #pragma unroll
                for (int r = 0; r < 4; ++r) {
                    float p = exp2f(sacc[qi][nt][r] - mnew[r]);
                    sacc[qi][nt][r] = p;
                    rsum[r] += p;
                }
            #pragma unroll
            for (int r = 0; r < 4; ++r) {
                float v0 = rsum[r];
                #pragma unroll
                for (int d = 1; d < 16; d <<= 1) v0 += __shfl_xor(v0, d);
                lrun[qi][r] = lrun[qi][r] * alpha[r] + v0;
                mrun[qi][r] = mnew[r];
            }
            #pragma unroll
            for (int i = 0; i < 8; ++i)
                #pragma unroll
                for (int r = 0; r < 4; ++r) oacc[qi][i][r] *= alpha[r];

            // ---- P: C-layout -> LDS (swizzled, per-wave region, no barrier) ----
            char* pb = smem + 32768 + (wid * 2 + qi) * 2048;
            #pragma unroll
            for (int nt = 0; nt < 4; ++nt)
                #pragma unroll
                for (int r = 0; r < 4; ++r) {
                    int row = quad * 4 + r;
                    int j = nt * 2 + (l16 >> 3);
                    *(bf16*)(pb + row * 128 + swz(j, row) * 16 + (l16 & 7) * 2) = (bf16)sacc[qi][nt][r];
                }
        }

        // ---- read P as A-frags, PV: 16 vf reads, 32 MFMA ----
        bf16x8 pf[2][2];
        #pragma unroll
        for (int qi = 0; qi < 2; ++qi) {
            char* pb = smem + 32768 + (wid * 2 + qi) * 2048;
            #pragma unroll
            for (int ks = 0; ks < 2; ++ks)
                pf[qi][ks] = *(const bf16x8*)(pb + l16 * 128 + swz(ks * 4 + quad, l16) * 16);
        }
        #pragma unroll
        for (int dht = 0; dht < 8; ++dht) {
            #pragma unroll
            for (int ks = 0; ks < 2; ++ks) {
                bf16x8 vf = *(const bf16x8*)(Vsh + (dht * 16 + l16) * 128 + swz(ks * 4 + quad, l16) * 16);
                oacc[0][dht] = __builtin_amdgcn_mfma_f32_16x16x32_bf16(pf[0][ks], vf, oacc[0][dht], 0, 0, 0);
                oacc[1][dht] = __builtin_amdgcn_mfma_f32_16x16x32_bf16(pf[1][ks], vf, oacc[1][dht], 0, 0, 0);
            }
        }
    }

    #pragma unroll
    for (int qi = 0; qi < 2; ++qi)
        #pragma unroll
        for (int dht = 0; dht < 8; ++dht)
            #pragma unroll
            for (int r = 0; r < 4; ++r) {
                int s = s0 + qi * 16 + quad * 4 + r;
                float v = oacc[qi][dht][r] / lrun[qi][r];
                ab[((size_t)(b * 2048 + s)) * 2048 + h * 128 + dht * 16 + l16] = (bf16)v;
            }
}

// ---------------- launch ----------------
extern "C" void kernel_launch(void* const* d_in, const int* in_sizes, int n_in,
                              void* d_out, int out_size, void* d_ws, size_t ws_size,
                              hipStream_t stream) {
    const float* x        = (const float*)d_in[0];
    const float* cached_k = (const float*)d_in[1];
    const float* cached_v = (const float*)d_in[2];
    const float* W_q      = (const float*)d_in[3];
    const float* W_k      = (const float*)d_in[4];
    const float* W_v      = (const float*)d_in[5];
    const float* W_o      = (const float*)d_in[6];

    float* out  = (float*)d_out;
    float* kout = out + 8388608;
    float* vout = out + 25165824;

    char* ws = (char*)d_ws;
    size_t off = 0;
    auto alloc = [&](size_t elts) { bf16* p = (bf16*)(ws + off); off += elts * 2; return p; };
    bf16* xb  = alloc(8388608);
    bf16* wqb = alloc(4194304);
    bf16* wkb = alloc(4194304);
    bf16* wvb = alloc(4194304);
    bf16* wob = alloc(4194304);
    bf16* qb  = alloc(8388608);
    bf16* kb  = alloc(16777216);
    bf16* vtb = alloc(16777216);
    bf16* ab  = alloc(8388608);

    conv_bf16<<<8192, 256, 0, stream>>>(x, xb, 2097152);
    conv_bf16<<<4096, 256, 0, stream>>>(W_q, wqb, 1048576);
    conv_bf16<<<4096, 256, 0, stream>>>(W_k, wkb, 1048576);
    conv_bf16<<<4096, 256, 0, stream>>>(W_v, wvb, 1048576);
    conv_bf16<<<4096, 256, 0, stream>>>(W_o, wob, 1048576);
    copy_cache_k<<<8192, 256, 0, stream>>>(cached_k, kout, kb);
    copy_cache_v<<<dim3(64, 4, 32), dim3(32, 8), 0, stream>>>(cached_v, vout, vtb);

    gemm_nt<1><<<dim3(16, 32), 256, 0, stream>>>(xb, wqb, nullptr, qb);
    gemm_nt<2><<<dim3(16, 32), 256, 0, stream>>>(xb, wkb, kout, kb);
    gemm_nt<3><<<dim3(16, 32), 256, 0, stream>>>(xb, wvb, vout, vtb);

    flash_attn<<<dim3(16, 32), 256, 0, stream>>>(qb, kb, vtb, ab);

    gemm_nt<0><<<dim3(16, 32), 256, 0, stream>>>(ab, wob, out, nullptr);
}

// Round 3
// 811.957 us; speedup vs baseline: 1.9650x; 1.2955x over previous
//
#include <hip/hip_runtime.h>

typedef __bf16 bf16;
typedef __bf16 bf16x4 __attribute__((ext_vector_type(4)));
typedef __bf16 bf16x8 __attribute__((ext_vector_type(8)));
typedef float f32x4 __attribute__((ext_vector_type(4)));

#define LOG2E 1.44269504088896340736f
// 1/sqrt(128) * log2(e), folded into Q at projection time -> softmax runs in log2 domain
#define QSCALE 0.12751884935f

// ---------------- async global->LDS (width 16) ----------------
__device__ __forceinline__ void gload_lds16(const void* gp, void* lp) {
    __builtin_amdgcn_global_load_lds(
        (__attribute__((address_space(1))) void*)gp,
        (__attribute__((address_space(3))) void*)lp,
        16, 0, 0);
}

// XOR swizzle of 16B-chunk index within a row (low 3 bits), self-inverse.
__device__ __forceinline__ int swz(int j, int row) {
    return (j & 8) | ((j ^ row) & 7);
}

// ---------------- DPP 16-lane row reductions (VALU pipe, no LDS) ----------------
template <int CTRL>
__device__ __forceinline__ float dpp_mov(float x) {
    return __int_as_float(__builtin_amdgcn_update_dpp(
        0, __float_as_int(x), CTRL, 0xF, 0xF, true));
}
// ROW_ROR:n = 0x120|n ; rotation-based allreduce over the 16-lane DPP row
__device__ __forceinline__ float rowmax16(float v) {
    v = fmaxf(v, dpp_mov<0x121>(v));
    v = fmaxf(v, dpp_mov<0x122>(v));
    v = fmaxf(v, dpp_mov<0x124>(v));
    v = fmaxf(v, dpp_mov<0x128>(v));
    return v;
}
__device__ __forceinline__ float rowsum16(float v) {
    v += dpp_mov<0x121>(v);
    v += dpp_mov<0x122>(v);
    v += dpp_mov<0x124>(v);
    v += dpp_mov<0x128>(v);
    return v;
}

// ---------------- fp32 -> bf16 convert ----------------
__global__ void conv_bf16(const float* __restrict__ in, bf16* __restrict__ out, int n4) {
    int i = blockIdx.x * 256 + threadIdx.x;
    if (i < n4) {
        float4 f = ((const float4*)in)[i];
        bf16x4 v;
        v[0] = (bf16)f.x; v[1] = (bf16)f.y; v[2] = (bf16)f.z; v[3] = (bf16)f.w;
        *(bf16x4*)(out + (size_t)i * 4) = v;
    }
}

// ---------------- cached_k -> d_out(k, t<2048) fp32 + kb bf16 ----------------
__global__ void copy_cache_k(const float* __restrict__ ck, float* __restrict__ kout,
                             bf16* __restrict__ kb) {
    size_t i = ((size_t)blockIdx.x * 256 + threadIdx.x) * 4;
    size_t bh  = i >> 18;
    size_t rem = i & 262143;
    size_t o   = (bh << 19) + rem;
    float4 f = *(const float4*)(ck + i);
    *(float4*)(kout + o) = f;
    bf16x4 v;
    v[0] = (bf16)f.x; v[1] = (bf16)f.y; v[2] = (bf16)f.z; v[3] = (bf16)f.w;
    *(bf16x4*)(kb + o) = v;
}

// ---------------- cached_v -> d_out(v, t<2048) fp32 + vtb bf16 transposed ----------------
__global__ void copy_cache_v(const float* __restrict__ cv, float* __restrict__ vout,
                             bf16* __restrict__ vtb) {
    __shared__ float tile[32][33];
    int bh = blockIdx.z;
    int t0 = blockIdx.x * 32;
    int dh0 = blockIdx.y * 32;
    int tx = threadIdx.x, ty = threadIdx.y;
    const float* src = cv + (size_t)bh * 2048 * 128;
    float* dstf = vout + (size_t)bh * 4096 * 128;
    #pragma unroll
    for (int i = 0; i < 4; ++i) {
        int t = t0 + ty * 4 + i;
        float val = src[(size_t)t * 128 + dh0 + tx];
        dstf[(size_t)t * 128 + dh0 + tx] = val;
        tile[ty * 4 + i][tx] = val;
    }
    __syncthreads();
    bf16* dstb = vtb + (size_t)bh * 128 * 4096;
    #pragma unroll
    for (int i = 0; i < 4; ++i) {
        int dh = dh0 + ty * 4 + i;
        dstb[(size_t)dh * 4096 + t0 + tx] = (bf16)tile[tx][ty * 4 + i];
    }
}

// ---------------- NT GEMM: C[M,N] = A[M,K] * B[N,K]^T, bf16 in, fp32 acc ----------------
template <int MODE>
__global__ __launch_bounds__(256)
void gemm_nt(const bf16* __restrict__ A, const bf16* __restrict__ Bm,
             float* __restrict__ out_f32, bf16* __restrict__ out_bf16) {
    const int K = 2048, N = 2048;
    __shared__ __align__(16) char smem[16384];
    const int tid = threadIdx.x;
    const int wid = tid >> 6;
    const int lane = tid & 63;
    const int quad = lane >> 4;
    const int l16 = lane & 15;
    const int m0 = blockIdx.y * 128;
    const int n0 = blockIdx.x * 128;
    const int wm = (wid & 1) * 64;
    const int wn = (wid >> 1) * 64;

    f32x4 zero = {0.f, 0.f, 0.f, 0.f};
    f32x4 acc[4][4];
    #pragma unroll
    for (int i = 0; i < 4; ++i)
        #pragma unroll
        for (int j = 0; j < 4; ++j) acc[i][j] = zero;

    for (int k0 = 0; k0 < K; k0 += 32) {
        #pragma unroll
        for (int t = 0; t < 2; ++t) {
            int c = t * 256 + tid;
            int row = c >> 2, kc = c & 3;
            const char* gA = (const char*)(A + (size_t)(m0 + row) * K + k0 + kc * 8);
            const char* gB = (const char*)(Bm + (size_t)(n0 + row) * K + k0 + kc * 8);
            char* lA = smem + (size_t)(t * 256 + (tid & ~63)) * 16;
            char* lB = smem + 8192 + (size_t)(t * 256 + (tid & ~63)) * 16;
            gload_lds16(gA, lA);
            gload_lds16(gB, lB);
        }
        __syncthreads();
        bf16x8 af[4], bfv[4];
        #pragma unroll
        for (int i = 0; i < 4; ++i) {
            af[i]  = *(const bf16x8*)(smem + ((wm + i * 16 + l16) * 32 + quad * 8) * 2);
            bfv[i] = *(const bf16x8*)(smem + 8192 + ((wn + i * 16 + l16) * 32 + quad * 8) * 2);
        }
        #pragma unroll
        for (int i = 0; i < 4; ++i)
            #pragma unroll
            for (int j = 0; j < 4; ++j)
                acc[i][j] = __builtin_amdgcn_mfma_f32_16x16x32_bf16(af[i], bfv[j], acc[i][j], 0, 0, 0);
        __syncthreads();
    }

    #pragma unroll
    for (int i = 0; i < 4; ++i)
        #pragma unroll
        for (int j = 0; j < 4; ++j)
            #pragma unroll
            for (int r = 0; r < 4; ++r) {
                int grow = m0 + wm + i * 16 + quad * 4 + r;
                int gcol = n0 + wn + j * 16 + l16;
                float v = acc[i][j][r];
                if (MODE == 0) {
                    out_f32[(size_t)grow * N + gcol] = v;
                } else {
                    int b = grow >> 11, s = grow & 2047;
                    int h = gcol >> 7, dh = gcol & 127;
                    if (MODE == 1) {
                        out_bf16[(((size_t)(b * 16 + h) * 2048) + s) * 128 + dh] = (bf16)(v * QSCALE);
                    } else if (MODE == 2) {
                        size_t idx = (((size_t)(b * 16 + h) * 4096) + 2048 + s) * 128 + dh;
                        out_f32[idx] = v;
                        out_bf16[idx] = (bf16)v;
                    } else {
                        size_t idx = (((size_t)(b * 16 + h) * 4096) + 2048 + s) * 128 + dh;
                        out_f32[idx] = v;
                        out_bf16[(((size_t)(b * 16 + h) * 128) + dh) * 4096 + 2048 + s] = (bf16)v;
                    }
                }
            }
}

// ---------------- flash attention v3 ----------------
// qb (B,H,2048,128) bf16 PRE-SCALED; kb (B,H,4096,128); vtb (B,H,128,4096) -> ab (B,S,2048)
// Grid: 512 flat blocks, XCD-swizzled so all 16 Q-blocks of one head share an XCD L2.
// Softmax reductions on DPP rows (VALU), pbuf stride 136B (conflict-free).
__global__ __launch_bounds__(256, 3)
void flash_attn(const bf16* __restrict__ qb, const bf16* __restrict__ kb,
                const bf16* __restrict__ vtb, bf16* __restrict__ ab) {
    // LDS: K tile [0,16384), V tile [16384,32768), pbuf [32768, 32768+8*2176)
    __shared__ __align__(16) char smem[50176];
    const int tid = threadIdx.x;
    const int wid = tid >> 6;
    const int lane = tid & 63;
    const int quad = lane >> 4;
    const int l16 = lane & 15;

    // XCD swizzle: flat = 512 blocks; same head -> same XCD
    const int flat = blockIdx.x;
    const int xcd = flat & 7;
    const int idx = flat >> 3;
    const int bh = xcd * 4 + (idx >> 4);
    const int qblk = idx & 15;
    const int b = bh >> 4, h = bh & 15;
    const int s0 = qblk * 128 + wid * 32;

    const bf16* Q  = qb  + (size_t)bh * 2048 * 128;
    const bf16* Kp = kb  + (size_t)bh * 4096 * 128;
    const bf16* Vt = vtb + (size_t)bh * 128 * 4096;

    bf16x8 qf[2][4];
    #pragma unroll
    for (int qi = 0; qi < 2; ++qi)
        #pragma unroll
        for (int ks = 0; ks < 4; ++ks)
            qf[qi][ks] = *(const bf16x8*)(Q + (size_t)(s0 + qi * 16 + l16) * 128 + ks * 32 + quad * 8);

    f32x4 zero = {0.f, 0.f, 0.f, 0.f};
    f32x4 oacc[2][8];
    float mrun[2][4], lrun[2][4];
    #pragma unroll
    for (int qi = 0; qi < 2; ++qi) {
        #pragma unroll
        for (int i = 0; i < 8; ++i) oacc[qi][i] = zero;
        #pragma unroll
        for (int r = 0; r < 4; ++r) { mrun[qi][r] = -1e30f; lrun[qi][r] = 0.f; }
    }

    char* const Ksh = smem;
    char* const Vsh = smem + 16384;

    for (int t0 = 0; t0 < 4096; t0 += 64) {
        __syncthreads();
        #pragma unroll
        for (int r = 0; r < 4; ++r) {
            int kc = r * 256 + tid;
            int row = kc >> 4, p = kc & 15;
            int j = swz(p, row);
            gload_lds16(Kp + (size_t)(t0 + row) * 128 + j * 8, Ksh + kc * 16);
        }
        #pragma unroll
        for (int r = 0; r < 4; ++r) {
            int vc = r * 256 + tid;
            int row = vc >> 3, p = vc & 7;
            int j = (p ^ row) & 7;
            gload_lds16(Vt + (size_t)row * 4096 + t0 + j * 8, Vsh + vc * 16);
        }
        __syncthreads();

        // ---- QK^T ----
        f32x4 sacc[2][4];
        #pragma unroll
        for (int qi = 0; qi < 2; ++qi)
            #pragma unroll
            for (int nt = 0; nt < 4; ++nt) sacc[qi][nt] = zero;
        #pragma unroll
        for (int nt = 0; nt < 4; ++nt) {
            #pragma unroll
            for (int ks = 0; ks < 4; ++ks) {
                bf16x8 kf = *(const bf16x8*)(Ksh + (nt * 16 + l16) * 256 + swz(ks * 4 + quad, l16) * 16);
                sacc[0][nt] = __builtin_amdgcn_mfma_f32_16x16x32_bf16(qf[0][ks], kf, sacc[0][nt], 0, 0, 0);
                sacc[1][nt] = __builtin_amdgcn_mfma_f32_16x16x32_bf16(qf[1][ks], kf, sacc[1][nt], 0, 0, 0);
            }
        }

        // ---- online softmax (log2 domain), DPP row reductions ----
        #pragma unroll
        for (int qi = 0; qi < 2; ++qi) {
            float mx[4];
            #pragma unroll
            for (int r = 0; r < 4; ++r) {
                float v0 = fmaxf(fmaxf(sacc[qi][0][r], sacc[qi][1][r]),
                                 fmaxf(sacc[qi][2][r], sacc[qi][3][r]));
                mx[r] = rowmax16(v0);
            }
            float alpha[4], mnew[4], rsum[4];
            #pragma unroll
            for (int r = 0; r < 4; ++r) {
                mnew[r] = fmaxf(mrun[qi][r], mx[r]);
                alpha[r] = __builtin_amdgcn_exp2f(mrun[qi][r] - mnew[r]);
                rsum[r] = 0.f;
            }
            #pragma unroll
            for (int nt = 0; nt < 4; ++nt)
                #pragma unroll
                for (int r = 0; r < 4; ++r) {
                    float p = __builtin_amdgcn_exp2f(sacc[qi][nt][r] - mnew[r]);
                    sacc[qi][nt][r] = p;
                    rsum[r] += p;
                }
            #pragma unroll
            for (int r = 0; r < 4; ++r) {
                lrun[qi][r] = lrun[qi][r] * alpha[r] + rowsum16(rsum[r]);
                mrun[qi][r] = mnew[r];
            }
            #pragma unroll
            for (int i = 0; i < 8; ++i)
                #pragma unroll
                for (int r = 0; r < 4; ++r) oacc[qi][i][r] *= alpha[r];

            // ---- P: C-layout -> LDS (per-wave region, stride 136, no barrier) ----
            char* pb = smem + 32768 + (wid * 2 + qi) * 2176;
            #pragma unroll
            for (int nt = 0; nt < 4; ++nt)
                #pragma unroll
                for (int r = 0; r < 4; ++r) {
                    int row = quad * 4 + r;
                    *(bf16*)(pb + row * 136 + nt * 32 + l16 * 2) = (bf16)sacc[qi][nt][r];
                }
        }

        // ---- PV ----
        bf16x8 pf[2][2];
        #pragma unroll
        for (int qi = 0; qi < 2; ++qi) {
            char* pb = smem + 32768 + (wid * 2 + qi) * 2176;
            #pragma unroll
            for (int ks = 0; ks < 2; ++ks)
                pf[qi][ks] = *(const bf16x8*)(pb + l16 * 136 + (ks * 4 + quad) * 16);
        }
        #pragma unroll
        for (int dht = 0; dht < 8; ++dht) {
            #pragma unroll
            for (int ks = 0; ks < 2; ++ks) {
                bf16x8 vf = *(const bf16x8*)(Vsh + (dht * 16 + l16) * 128 + swz(ks * 4 + quad, l16) * 16);
                oacc[0][dht] = __builtin_amdgcn_mfma_f32_16x16x32_bf16(pf[0][ks], vf, oacc[0][dht], 0, 0, 0);
                oacc[1][dht] = __builtin_amdgcn_mfma_f32_16x16x32_bf16(pf[1][ks], vf, oacc[1][dht], 0, 0, 0);
            }
        }
    }

    #pragma unroll
    for (int qi = 0; qi < 2; ++qi)
        #pragma unroll
        for (int dht = 0; dht < 8; ++dht)
            #pragma unroll
            for (int r = 0; r < 4; ++r) {
                int s = s0 + qi * 16 + quad * 4 + r;
                float v = oacc[qi][dht][r] / lrun[qi][r];
                ab[((size_t)(b * 2048 + s)) * 2048 + h * 128 + dht * 16 + l16] = (bf16)v;
            }
}

// ---------------- launch ----------------
extern "C" void kernel_launch(void* const* d_in, const int* in_sizes, int n_in,
                              void* d_out, int out_size, void* d_ws, size_t ws_size,
                              hipStream_t stream) {
    const float* x        = (const float*)d_in[0];
    const float* cached_k = (const float*)d_in[1];
    const float* cached_v = (const float*)d_in[2];
    const float* W_q      = (const float*)d_in[3];
    const float* W_k      = (const float*)d_in[4];
    const float* W_v      = (const float*)d_in[5];
    const float* W_o      = (const float*)d_in[6];

    float* out  = (float*)d_out;
    float* kout = out + 8388608;
    float* vout = out + 25165824;

    char* ws = (char*)d_ws;
    size_t off = 0;
    auto alloc = [&](size_t elts) { bf16* p = (bf16*)(ws + off); off += elts * 2; return p; };
    bf16* xb  = alloc(8388608);
    bf16* wqb = alloc(4194304);
    bf16* wkb = alloc(4194304);
    bf16* wvb = alloc(4194304);
    bf16* wob = alloc(4194304);
    bf16* qb  = alloc(8388608);
    bf16* kb  = alloc(16777216);
    bf16* vtb = alloc(16777216);
    bf16* ab  = alloc(8388608);

    conv_bf16<<<8192, 256, 0, stream>>>(x, xb, 2097152);
    conv_bf16<<<4096, 256, 0, stream>>>(W_q, wqb, 1048576);
    conv_bf16<<<4096, 256, 0, stream>>>(W_k, wkb, 1048576);
    conv_bf16<<<4096, 256, 0, stream>>>(W_v, wvb, 1048576);
    conv_bf16<<<4096, 256, 0, stream>>>(W_o, wob, 1048576);
    copy_cache_k<<<8192, 256, 0, stream>>>(cached_k, kout, kb);
    copy_cache_v<<<dim3(64, 4, 32), dim3(32, 8), 0, stream>>>(cached_v, vout, vtb);

    gemm_nt<1><<<dim3(16, 32), 256, 0, stream>>>(xb, wqb, nullptr, qb);
    gemm_nt<2><<<dim3(16, 32), 256, 0, stream>>>(xb, wkb, kout, kb);
    gemm_nt<3><<<dim3(16, 32), 256, 0, stream>>>(xb, wvb, vout, vtb);

    flash_attn<<<512, 256, 0, stream>>>(qb, kb, vtb, ab);

    gemm_nt<0><<<dim3(16, 32), 256, 0, stream>>>(ab, wob, out, nullptr);
}